// Round 10
// baseline (168.900 us; speedup 1.0000x reference)
//
#include <hip/hip_runtime.h>

typedef int   v4i __attribute__((ext_vector_type(4)));
typedef float v4f __attribute__((ext_vector_type(4)));
typedef unsigned short ushort_t;

#define NB 32
#define CI 128
#define HW 56
#define KOC 256
#define HP 58
#define MTOT (NB*HW*HW)                  // 100352
#define XP_ELEMS ((size_t)NB*HP*HP*CI)   // 13778944
#define XP_OFF_BYTES ((size_t)1<<20)

__device__ __forceinline__ unsigned short f2bf(float f) {
    unsigned int u = __builtin_bit_cast(unsigned int, f);
    u += 0x7fffu + ((u >> 16) & 1u);   // round-to-nearest-even
    return (unsigned short)(u >> 16);
}

__device__ __forceinline__ void gload16(const void* g, void* l) {
    __builtin_amdgcn_global_load_lds(
        (const __attribute__((address_space(1))) void*)g,
        (__attribute__((address_space(3))) void*)l, 16, 0, 0);
}

// ---- weight (256,128,3,3) f32 -> Wb[rs][ko][c] bf16 (c contiguous)
__global__ void wt_bf16(const float* __restrict__ w, ushort_t* __restrict__ wb) {
    int t = blockIdx.x * 256 + threadIdx.x;      // t = ko*128 + c
    if (t >= KOC * CI) return;
    const float* src = w + (size_t)t * 9;
    int ko = t >> 7, c = t & 127;
    #pragma unroll
    for (int rs = 0; rs < 9; ++rs)
        wb[(size_t)(rs * KOC + ko) * CI + c] = f2bf(src[rs]);
}

// ---- x NCHW f32 -> padded NHWC bf16 Xp[n][58][58][128] (interior only)
__global__ void pad_nhwc_bf16(const float* __restrict__ x, ushort_t* __restrict__ xp) {
    __shared__ ushort_t tile[HW][136];
    int b = blockIdx.x;                          // n*56 + h
    int n = b / HW, h = b % HW;
    int tid = threadIdx.x;
    const float* xr = x + (size_t)n * CI * HW * HW + (size_t)h * HW;
    for (int idx = tid; idx < CI * HW; idx += 256) {
        int c = idx / HW, w = idx % HW;
        tile[w][c] = f2bf(xr[(size_t)c * (HW * HW) + w]);
    }
    __syncthreads();
    ushort_t* xpr = xp + ((size_t)(n * HP + (h + 1)) * HP + 1) * CI;
    for (int idx = tid; idx < (HW * CI) / 8; idx += 256) {
        int w = idx >> 4, c8 = (idx & 15) * 8;
        *reinterpret_cast<uint4*>(xpr + (size_t)w * CI + c8) =
            *reinterpret_cast<const uint4*>(&tile[w][c8]);
    }
}

// ---- zero only the padding border of Xp
__global__ void border_zero(ushort_t* __restrict__ xp) {
    int t = blockIdx.x * 256 + threadIdx.x;
    if (t >= NB * 228 * 16) return;
    int c16 = t & 15;
    int p = (t >> 4) % 228;
    int n = t / (228 * 16);
    int h, wc;
    if (p < 58)       { h = 0;               wc = p; }
    else if (p < 116) { h = 57;              wc = p - 58; }
    else { int q = p - 116; h = 1 + (q >> 1); wc = (q & 1) * 57; }
    size_t off = ((size_t)(n * HP + h) * HP + wc) * CI + (size_t)c16 * 8;
    uint4 z; z.x = z.y = z.z = z.w = 0u;
    *reinterpret_cast<uint4*>(xp + off) = z;
}

// ============ main conv: A via dbuf-LDS DMA; B in REGISTERS, depth-2 prefetch ====
// 128(ko) x 128(m) tile, BK=32, 4 waves of 64x64, 36 K-steps, 4 blocks/CU.
// LDS = A only: 2 planes x 8 KB. Per iter t:
//   {4x ds_read A(plane t); DMA A(t+1)->plane^1; SCHB (pins DMA order);
//    lgkmcnt(0); SCHB; 16 MFMA w/ B-set(t&1); 4x global_load B(t+2)->set(t&1);
//    vmcnt(4)  [queue: B(t+1),DMA(t+1),B(t+2) -> keeps B(t+2), retires rest];
//    s_barrier}.
// B(t) is loaded 2 iters ahead -> L2 latency fully covered.
// R9 bug fixed: prologue B(1) offset is rs=0 CHUNK 1 = 64 bytes (was 256).

#define BODY(POFF, BFS, IT, DO_STAGE, DO_BLOAD, VMSTMT, DO_BAR) do {              \
    _Pragma("unroll")                                                             \
    for (int a = 0; a < 4; ++a)                                                   \
        asm volatile("ds_read_b128 %0, %1 offset:" #POFF                          \
                     : "=v"(af[a]) : "v"(aAddr[a]));                              \
    if (DO_STAGE) {                                                               \
        const int itn = (IT) + 1;                                                 \
        const int rsn = itn >> 2;                                                 \
        const size_t woffn = (size_t)rsn * (KOC * CI) + (itn & 3) * 32;           \
        char* dst = ldsBase + ((POFF) ^ 8192);                                    \
        gload16(wb + wS0 + woffn, dst);                                           \
        gload16(wb + wS1 + woffn, dst + 4096);                                    \
    }                                                                             \
    __builtin_amdgcn_sched_barrier(0);  /* pin DMA issue before B-loads */        \
    asm volatile("s_waitcnt lgkmcnt(0)");                                         \
    __builtin_amdgcn_sched_barrier(0);                                            \
    __builtin_amdgcn_s_setprio(1);                                                \
    _Pragma("unroll")                                                             \
    for (int a = 0; a < 4; ++a)                                                   \
        _Pragma("unroll")                                                         \
        for (int b = 0; b < 4; ++b)                                               \
            asm volatile("v_mfma_f32_16x16x32_bf16 %0, %1, %2, %0"                \
                         : "+v"(acc[a][b]) : "v"(af[a]), "v"(BFS[b]));            \
    __builtin_amdgcn_s_setprio(0);                                                \
    if (DO_BLOAD) {                                                               \
        const int itb = (IT) + 2;                                                 \
        const int rsb = itb >> 2;                                                 \
        const int rb = (rsb * 11) >> 5, sb = rsb - rb * 3;                        \
        const unsigned xstep =                                                    \
            (unsigned)(((rb * HP + sb) * CI + (itb & 3) * 32) * 2);               \
        _Pragma("unroll")                                                         \
        for (int b = 0; b < 4; ++b)                                               \
            asm volatile("global_load_dwordx4 %0, %1, %2"                         \
                         : "=v"(BFS[b]) : "v"(xoff[b] + xstep), "s"(xp));         \
    }                                                                             \
    VMSTMT;                                                                       \
    if (DO_BAR) __builtin_amdgcn_s_barrier();                                     \
} while (0)

__global__ __launch_bounds__(256, 4) void conv_mfma(
    const ushort_t* __restrict__ xp,
    const ushort_t* __restrict__ wb,
    const float* __restrict__ bias,
    float* __restrict__ out)
{
    __shared__ alignas(16) ushort_t sA[2][4096];   // A only: 2 planes x 8 KB

    const int tid  = threadIdx.x;
    const int lane = tid & 63;
    const int wv   = tid >> 6;                    // 0..3
    const int wko  = wv >> 1, wm = wv & 1;        // 2x2 waves of 64x64
    // XCD-aware bijective swizzle: 1568 blocks = 8 XCDs x 196 contiguous
    const int bid   = blockIdx.x;
    const int chunk = (bid & 7) * 196 + (bid >> 3);
    const int mt = chunk >> 1, kt = chunk & 1;    // adjacent chunks share m-tile
    const int m0 = mt * 128, ko0 = kt * 128;
    const int lm = lane & 15, lk = lane >> 4;

    // ---- A staging sources (DMA): instr q covers rows q*64 + wv*16 + (lane>>2)
    const int sc   = (lane & 3) ^ ((lane >> 3) & 3);  // inverse-swizzled 16B chunk
    const int row0 = wv * 16 + (lane >> 2);
    const size_t wS0 = (size_t)(ko0 + row0) * CI + sc * 8;
    const size_t wS1 = (size_t)(ko0 + 64 + row0) * CI + sc * 8;
    char* ldsBase = (char*)&sA[0][0] + wv * 1024;     // wave-uniform DMA dest base

    // ---- A fragment LDS byte addresses (plane 0; plane 1 via offset:8192)
    unsigned aAddr[4];
    #pragma unroll
    for (int a = 0; a < 4; ++a) {
        int row = wko * 64 + a * 16 + lm;
        aAddr[a] = (unsigned)(size_t)&sA[0][0]
                 + (unsigned)(row * 64 + (lk ^ ((row >> 1) & 3)) * 16);
    }

    // ---- B direct-load byte offsets (per-lane pixel base + k-subchunk)
    unsigned xoff[4];
    #pragma unroll
    for (int b = 0; b < 4; ++b) {
        int mm = m0 + wm * 64 + b * 16 + lm;
        int n = mm / 3136, tt = mm % 3136, oh = tt / 56, ow = tt % 56;
        xoff[b] = (unsigned)((((size_t)(n * HP + oh) * HP + ow) * CI + lk * 8) * 2);
    }

    v4f acc[4][4];
    const v4f vzero = {0.f, 0.f, 0.f, 0.f};
    #pragma unroll
    for (int a = 0; a < 4; ++a)
        #pragma unroll
        for (int b = 0; b < 4; ++b) acc[a][b] = vzero;

    v4i af[4], bf0[4], bf1[4];

    // ---- prologue: DMA A(0) -> plane0; load B(0)->set0, B(1)->set1
    gload16(wb + wS0, ldsBase);
    gload16(wb + wS1, ldsBase + 4096);
    __builtin_amdgcn_sched_barrier(0);
    #pragma unroll
    for (int b = 0; b < 4; ++b)
        asm volatile("global_load_dwordx4 %0, %1, %2"
                     : "=v"(bf0[b]) : "v"(xoff[b]), "s"(xp));
    {
        // B(1): it=1 -> rs=0 (r=0,s=0), chunk=1 -> offset 32 elems = 64 BYTES
        const unsigned xs1 = 64u;
        #pragma unroll
        for (int b = 0; b < 4; ++b)
            asm volatile("global_load_dwordx4 %0, %1, %2"
                         : "=v"(bf1[b]) : "v"(xoff[b] + xs1), "s"(xp));
    }
    asm volatile("s_waitcnt vmcnt(4)");   // retire DMA(0)+B(0); B(1) in flight
    __builtin_amdgcn_s_barrier();

    // ---- main loop: t = 0..33 (17 pairs), then peeled 34, 35
    for (int t = 0; t < 17; ++t) {
        BODY(0,    bf0, 2 * t,     true, true,
             asm volatile("s_waitcnt vmcnt(4)"), true);
        BODY(8192, bf1, 2 * t + 1, true, true,
             asm volatile("s_waitcnt vmcnt(4)"), true);
    }
    BODY(0,    bf0, 34, true,  false,
         asm volatile("s_waitcnt vmcnt(0)"), true);   // drain B(35)+DMA(35)
    BODY(8192, bf1, 35, false, false, (void)0, false);

    // ---- MFMA->VALU hazard fence
    asm volatile("s_nop 7\n\ts_nop 7\n\ts_nop 7"
        : "+v"(acc[0][0]), "+v"(acc[0][1]), "+v"(acc[0][2]), "+v"(acc[0][3]),
          "+v"(acc[1][0]), "+v"(acc[1][1]), "+v"(acc[1][2]), "+v"(acc[1][3]),
          "+v"(acc[2][0]), "+v"(acc[2][1]), "+v"(acc[2][2]), "+v"(acc[2][3]),
          "+v"(acc[3][0]), "+v"(acc[3][1]), "+v"(acc[3][2]), "+v"(acc[3][3]));

    // ---- epilogue: D row=(lane>>4)*4+r -> ko ; col=lane&15 -> m
    const int koB = ko0 + wko * 64 + lk * 4;
    v4f bv[4];
    #pragma unroll
    for (int a = 0; a < 4; ++a)
        bv[a] = *reinterpret_cast<const v4f*>(bias + koB + a * 16);

    #pragma unroll
    for (int bb = 0; bb < 4; ++bb) {
        int mcol = m0 + wm * 64 + bb * 16 + lm;
        int n = mcol / 3136, t4 = mcol % 3136, oh = t4 / 56, ow = t4 % 56;
        size_t obase = (size_t)n * (KOC * 3136) + (size_t)oh * 56 + ow;
        #pragma unroll
        for (int a = 0; a < 4; ++a) {
            int kk = koB + a * 16;
            #pragma unroll
            for (int r = 0; r < 4; ++r)
                out[obase + (size_t)(kk + r) * 3136] = acc[a][bb][r] + bv[a][r];
        }
    }
}

// ---- insurance path if workspace is too small
__global__ void conv_naive(const float* __restrict__ x, const float* __restrict__ w,
                           const float* __restrict__ bias, float* __restrict__ out) {
    int idx = blockIdx.x * 256 + threadIdx.x;
    if (idx >= NB * KOC * HW * HW) return;
    int ow = idx % 56, t = idx / 56, oh = t % 56, t2 = t / 56, ko = t2 % 256, n = t2 / 256;
    float accv = bias[ko];
    for (int c = 0; c < CI; ++c)
        for (int r = 0; r < 3; ++r) {
            int ih = oh - 1 + r;
            if (ih < 0 || ih >= HW) continue;
            for (int s = 0; s < 3; ++s) {
                int iw = ow - 1 + s;
                if (iw < 0 || iw >= HW) continue;
                accv += x[((size_t)(n * CI + c) * HW + ih) * HW + iw] *
                        w[((size_t)(ko * CI + c) * 3 + r) * 3 + s];
            }
        }
    out[idx] = accv;
}

extern "C" void kernel_launch(void* const* d_in, const int* in_sizes, int n_in,
                              void* d_out, int out_size, void* d_ws, size_t ws_size,
                              hipStream_t stream) {
    const float* x    = (const float*)d_in[0];
    const float* w    = (const float*)d_in[1];
    const float* bias = (const float*)d_in[2];
    float* out = (float*)d_out;

    size_t need = XP_OFF_BYTES + XP_ELEMS * 2;
    if (ws_size < need) {
        int tot = NB * KOC * HW * HW;
        conv_naive<<<dim3((tot + 255) / 256), dim3(256), 0, stream>>>(x, w, bias, out);
        return;
    }

    ushort_t* wbp = (ushort_t*)d_ws;
    ushort_t* xpd = (ushort_t*)((char*)d_ws + XP_OFF_BYTES);

    border_zero<<<dim3((NB * 228 * 16 + 255) / 256), dim3(256), 0, stream>>>(xpd);
    wt_bf16<<<dim3((KOC * CI + 255) / 256), dim3(256), 0, stream>>>(w, wbp);
    pad_nhwc_bf16<<<dim3(NB * HW), dim3(256), 0, stream>>>(x, xpd);

    conv_mfma<<<dim3((MTOT / 128) * 2), dim3(256), 0, stream>>>(xpd, wbp, bias, out);
}

// Round 11
// 104.486 us; speedup vs baseline: 1.6165x; 1.6165x over previous
//
#include <hip/hip_runtime.h>

typedef int   v4i __attribute__((ext_vector_type(4)));
typedef float v4f __attribute__((ext_vector_type(4)));
typedef unsigned short ushort_t;

#define NB 32
#define CI 128
#define HW 56
#define KOC 256
#define HP 58
#define MTOT (NB*HW*HW)                  // 100352
#define XP_ELEMS ((size_t)NB*HP*HP*CI)   // 13778944
#define XP_OFF_BYTES ((size_t)1<<20)

__device__ __forceinline__ unsigned short f2bf(float f) {
    unsigned int u = __builtin_bit_cast(unsigned int, f);
    u += 0x7fffu + ((u >> 16) & 1u);   // round-to-nearest-even
    return (unsigned short)(u >> 16);
}

__device__ __forceinline__ void gload16(const void* g, void* l) {
    __builtin_amdgcn_global_load_lds(
        (const __attribute__((address_space(1))) void*)g,
        (__attribute__((address_space(3))) void*)l, 16, 0, 0);
}

// ---- weight (256,128,3,3) f32 -> Wb[rs][ko][c] bf16 (c contiguous)
__global__ void wt_bf16(const float* __restrict__ w, ushort_t* __restrict__ wb) {
    int t = blockIdx.x * 256 + threadIdx.x;      // t = ko*128 + c
    if (t >= KOC * CI) return;
    const float* src = w + (size_t)t * 9;
    int ko = t >> 7, c = t & 127;
    #pragma unroll
    for (int rs = 0; rs < 9; ++rs)
        wb[(size_t)(rs * KOC + ko) * CI + c] = f2bf(src[rs]);
}

// ---- x NCHW f32 -> padded NHWC bf16 Xp[n][58][58][128] (interior only)
__global__ void pad_nhwc_bf16(const float* __restrict__ x, ushort_t* __restrict__ xp) {
    __shared__ ushort_t tile[HW][136];
    int b = blockIdx.x;                          // n*56 + h
    int n = b / HW, h = b % HW;
    int tid = threadIdx.x;
    const float* xr = x + (size_t)n * CI * HW * HW + (size_t)h * HW;
    for (int idx = tid; idx < CI * HW; idx += 256) {
        int c = idx / HW, w = idx % HW;
        tile[w][c] = f2bf(xr[(size_t)c * (HW * HW) + w]);
    }
    __syncthreads();
    ushort_t* xpr = xp + ((size_t)(n * HP + (h + 1)) * HP + 1) * CI;
    for (int idx = tid; idx < (HW * CI) / 8; idx += 256) {
        int w = idx >> 4, c8 = (idx & 15) * 8;
        *reinterpret_cast<uint4*>(xpr + (size_t)w * CI + c8) =
            *reinterpret_cast<const uint4*>(&tile[w][c8]);
    }
}

// ---- zero only the padding border of Xp
__global__ void border_zero(ushort_t* __restrict__ xp) {
    int t = blockIdx.x * 256 + threadIdx.x;
    if (t >= NB * 228 * 16) return;
    int c16 = t & 15;
    int p = (t >> 4) % 228;
    int n = t / (228 * 16);
    int h, wc;
    if (p < 58)       { h = 0;               wc = p; }
    else if (p < 116) { h = 57;              wc = p - 58; }
    else { int q = p - 116; h = 1 + (q >> 1); wc = (q & 1) * 57; }
    size_t off = ((size_t)(n * HP + h) * HP + wc) * CI + (size_t)c16 * 8;
    uint4 z; z.x = z.y = z.z = z.w = 0u;
    *reinterpret_cast<uint4*>(xp + off) = z;
}

// ======== main conv: R8 structure + asymmetric-depth staging =====================
// 128(ko) x 128(m), BK=32, 4 waves of 64x64, 36 K-steps, 40 KB LDS, 4 blocks/CU.
// A (W): 2 planes, depth-1 (L2-resident source, short latency OK).
// X    : 3 planes, depth-2 (L3-resident source: issue X(t+2) at iter t -> 2-iter
//        latency window). Per iter, pinned order: [A(t+1)x2][X(t+2)x2]; end-of-iter
//        vmcnt(2) retires {X(t+1),A(t+1)}, keeps X(t+2) in flight. Never 0 in loop.
// Plane cycling A mod2 / X mod3 -> period 6; ds_read offsets literal per position.

#define VMW(n) asm volatile("s_waitcnt vmcnt(" #n ")")
#define SCHB() __builtin_amdgcn_sched_barrier(0)

#define BODY(AOFF, XOFF, IT, DO_A, DO_X, VMSTMT, DO_BAR) do {                     \
    if (DO_A) {                                                                   \
        const int itn = (IT) + 1;                                                 \
        const int rsn = itn >> 2;                                                 \
        const size_t woffn = (size_t)rsn * (KOC * CI) + (itn & 3) * 32;           \
        char* dA_ = baseA + ((itn) & 1) * 8192;                                   \
        gload16(wb + wS0 + woffn, dA_);                                           \
        gload16(wb + wS1 + woffn, dA_ + 4096);                                    \
    }                                                                             \
    SCHB();  /* pin: A-DMAs before X-DMAs in the vmcnt queue */                   \
    if (DO_X) {                                                                   \
        const int itx = (IT) + 2;                                                 \
        const int rsx = itx >> 2;                                                 \
        const int rx = (rsx * 11) >> 5, sx = rsx - rx * 3;                        \
        const size_t xoffn = (size_t)(rx * HP + sx) * CI + (itx & 3) * 32;        \
        char* dX_ = baseX + ((itx) % 3) * 8192;                                   \
        gload16(xp + xS0 + xoffn, dX_);                                           \
        gload16(xp + xS1 + xoffn, dX_ + 4096);                                    \
    }                                                                             \
    SCHB();                                                                       \
    _Pragma("unroll")                                                             \
    for (int a = 0; a < 4; ++a)                                                   \
        asm volatile("ds_read_b128 %0, %1 offset:" #AOFF                          \
                     : "=v"(af[a]) : "v"(aAddr[a]));                              \
    _Pragma("unroll")                                                             \
    for (int b = 0; b < 4; ++b)                                                   \
        asm volatile("ds_read_b128 %0, %1 offset:" #XOFF                          \
                     : "=v"(bf[b]) : "v"(xAddr[b]));                              \
    asm volatile("s_waitcnt lgkmcnt(0)");                                         \
    SCHB();                                                                       \
    __builtin_amdgcn_s_setprio(1);                                                \
    _Pragma("unroll")                                                             \
    for (int a = 0; a < 4; ++a)                                                   \
        _Pragma("unroll")                                                         \
        for (int b = 0; b < 4; ++b)                                               \
            asm volatile("v_mfma_f32_16x16x32_bf16 %0, %1, %2, %0"                \
                         : "+v"(acc[a][b]) : "v"(af[a]), "v"(bf[b]));             \
    __builtin_amdgcn_s_setprio(0);                                                \
    VMSTMT;                                                                       \
    if (DO_BAR) __builtin_amdgcn_s_barrier();                                     \
} while (0)

__global__ __launch_bounds__(256, 4) void conv_mfma(
    const ushort_t* __restrict__ xp,
    const ushort_t* __restrict__ wb,
    const float* __restrict__ bias,
    float* __restrict__ out)
{
    __shared__ alignas(16) ushort_t sA[2][4096];   // A: 2 planes x 8 KB
    __shared__ alignas(16) ushort_t sX[3][4096];   // X: 3 planes x 8 KB

    const int tid  = threadIdx.x;
    const int lane = tid & 63;
    const int wv   = tid >> 6;                    // 0..3
    const int wko  = wv >> 1, wm = wv & 1;        // 2x2 waves of 64x64
    // XCD-aware bijective swizzle: 1568 blocks = 8 XCDs x 196 contiguous
    const int bid   = blockIdx.x;
    const int chunk = (bid & 7) * 196 + (bid >> 3);
    const int mt = chunk >> 1, kt = chunk & 1;    // adjacent chunks share m-tile
    const int m0 = mt * 128, ko0 = kt * 128;
    const int lm = lane & 15, lk = lane >> 4;

    // ---- staging sources (DMA): instr q covers rows q*64 + wv*16 + (lane>>2)
    const int sc   = (lane & 3) ^ ((lane >> 3) & 3);  // inverse-swizzled 16B chunk
    const int row0 = wv * 16 + (lane >> 2);
    const size_t wS0 = (size_t)(ko0 + row0) * CI + sc * 8;
    const size_t wS1 = (size_t)(ko0 + 64 + row0) * CI + sc * 8;
    size_t xS0, xS1;
    {
        int mm = m0 + row0;
        int n = mm / 3136, tt = mm % 3136, oh = tt / 56, ow = tt % 56;
        xS0 = ((size_t)(n * HP + oh) * HP + ow) * CI + sc * 8;
        mm = m0 + 64 + row0;
        n = mm / 3136; tt = mm % 3136; oh = tt / 56; ow = tt % 56;
        xS1 = ((size_t)(n * HP + oh) * HP + ow) * CI + sc * 8;
    }
    char* baseA = (char*)&sA[0][0] + wv * 1024;   // wave-uniform DMA dest bases
    char* baseX = (char*)&sX[0][0] + wv * 1024;

    // ---- fragment LDS byte addresses (plane 0; other planes via offset:)
    unsigned aAddr[4], xAddr[4];
    #pragma unroll
    for (int a = 0; a < 4; ++a) {
        int row = wko * 64 + a * 16 + lm;
        aAddr[a] = (unsigned)(size_t)&sA[0][0]
                 + (unsigned)(row * 64 + (lk ^ ((row >> 1) & 3)) * 16);
    }
    #pragma unroll
    for (int b = 0; b < 4; ++b) {
        int row = wm * 64 + b * 16 + lm;
        xAddr[b] = (unsigned)(size_t)&sX[0][0]
                 + (unsigned)(row * 64 + (lk ^ ((row >> 1) & 3)) * 16);
    }

    v4f acc[4][4];
    const v4f vzero = {0.f, 0.f, 0.f, 0.f};
    #pragma unroll
    for (int a = 0; a < 4; ++a)
        #pragma unroll
        for (int b = 0; b < 4; ++b) acc[a][b] = vzero;

    v4i af[4], bf[4];

    // ---- prologue: A(0)->Ap0; X(0)->Xp0; X(1)->Xp1 (X(1): rs=0 chunk=1 -> +32e)
    gload16(wb + wS0, baseA);
    gload16(wb + wS1, baseA + 4096);
    SCHB();
    gload16(xp + xS0, baseX);
    gload16(xp + xS1, baseX + 4096);
    gload16(xp + xS0 + 32, baseX + 8192);
    gload16(xp + xS1 + 32, baseX + 8192 + 4096);
    SCHB();
    VMW(2);                      // retire A(0),X(0); keep X(1) in flight
    __builtin_amdgcn_s_barrier();

    // ---- main loop: 5 full sextets (iters 0..29), then peeled 30..35
    for (int s = 0; s < 5; ++s) {
        const int ib = 6 * s;
        BODY(0,    0,     ib + 0, 1, 1, VMW(2), 1);
        BODY(8192, 8192,  ib + 1, 1, 1, VMW(2), 1);
        BODY(0,    16384, ib + 2, 1, 1, VMW(2), 1);
        BODY(8192, 0,     ib + 3, 1, 1, VMW(2), 1);
        BODY(0,    8192,  ib + 4, 1, 1, VMW(2), 1);
        BODY(8192, 16384, ib + 5, 1, 1, VMW(2), 1);
    }
    BODY(0,    0,     30, 1, 1, VMW(2), 1);
    BODY(8192, 8192,  31, 1, 1, VMW(2), 1);
    BODY(0,    16384, 32, 1, 1, VMW(2), 1);
    BODY(8192, 0,     33, 1, 1, VMW(2), 1);   // issues A(34), X(35)
    BODY(0,    8192,  34, 1, 0, VMW(0), 1);   // issues A(35); drain all
    BODY(8192, 16384, 35, 0, 0, (void)0, 0);

    // ---- MFMA->VALU hazard fence
    asm volatile("s_nop 7\n\ts_nop 7\n\ts_nop 7"
        : "+v"(acc[0][0]), "+v"(acc[0][1]), "+v"(acc[0][2]), "+v"(acc[0][3]),
          "+v"(acc[1][0]), "+v"(acc[1][1]), "+v"(acc[1][2]), "+v"(acc[1][3]),
          "+v"(acc[2][0]), "+v"(acc[2][1]), "+v"(acc[2][2]), "+v"(acc[2][3]),
          "+v"(acc[3][0]), "+v"(acc[3][1]), "+v"(acc[3][2]), "+v"(acc[3][3]));

    // ---- epilogue: D row=(lane>>4)*4+r -> ko ; col=lane&15 -> m
    const int koB = ko0 + wko * 64 + lk * 4;
    v4f bv[4];
    #pragma unroll
    for (int a = 0; a < 4; ++a)
        bv[a] = *reinterpret_cast<const v4f*>(bias + koB + a * 16);

    #pragma unroll
    for (int bb = 0; bb < 4; ++bb) {
        int mcol = m0 + wm * 64 + bb * 16 + lm;
        int n = mcol / 3136, t4 = mcol % 3136, oh = t4 / 56, ow = t4 % 56;
        size_t obase = (size_t)n * (KOC * 3136) + (size_t)oh * 56 + ow;
        #pragma unroll
        for (int a = 0; a < 4; ++a) {
            int kk = koB + a * 16;
            #pragma unroll
            for (int r = 0; r < 4; ++r)
                out[obase + (size_t)(kk + r) * 3136] = acc[a][bb][r] + bv[a][r];
        }
    }
}

// ---- insurance path if workspace is too small
__global__ void conv_naive(const float* __restrict__ x, const float* __restrict__ w,
                           const float* __restrict__ bias, float* __restrict__ out) {
    int idx = blockIdx.x * 256 + threadIdx.x;
    if (idx >= NB * KOC * HW * HW) return;
    int ow = idx % 56, t = idx / 56, oh = t % 56, t2 = t / 56, ko = t2 % 256, n = t2 / 256;
    float accv = bias[ko];
    for (int c = 0; c < CI; ++c)
        for (int r = 0; r < 3; ++r) {
            int ih = oh - 1 + r;
            if (ih < 0 || ih >= HW) continue;
            for (int s = 0; s < 3; ++s) {
                int iw = ow - 1 + s;
                if (iw < 0 || iw >= HW) continue;
                accv += x[((size_t)(n * CI + c) * HW + ih) * HW + iw] *
                        w[((size_t)(ko * CI + c) * 3 + r) * 3 + s];
            }
        }
    out[idx] = accv;
}

extern "C" void kernel_launch(void* const* d_in, const int* in_sizes, int n_in,
                              void* d_out, int out_size, void* d_ws, size_t ws_size,
                              hipStream_t stream) {
    const float* x    = (const float*)d_in[0];
    const float* w    = (const float*)d_in[1];
    const float* bias = (const float*)d_in[2];
    float* out = (float*)d_out;

    size_t need = XP_OFF_BYTES + XP_ELEMS * 2;
    if (ws_size < need) {
        int tot = NB * KOC * HW * HW;
        conv_naive<<<dim3((tot + 255) / 256), dim3(256), 0, stream>>>(x, w, bias, out);
        return;
    }

    ushort_t* wbp = (ushort_t*)d_ws;
    ushort_t* xpd = (ushort_t*)((char*)d_ws + XP_OFF_BYTES);

    border_zero<<<dim3((NB * 228 * 16 + 255) / 256), dim3(256), 0, stream>>>(xpd);
    wt_bf16<<<dim3((KOC * CI + 255) / 256), dim3(256), 0, stream>>>(w, wbp);
    pad_nhwc_bf16<<<dim3(NB * HW), dim3(256), 0, stream>>>(x, xpd);

    conv_mfma<<<dim3((MTOT / 128) * 2), dim3(256), 0, stream>>>(xpd, wbp, bias, out);
}